// Round 6
// baseline (901.561 us; speedup 1.0000x reference)
//
#include <hip/hip_runtime.h>
#include <hip/hip_bf16.h>
#include <hip/hip_fp16.h>

#define N_NODES 100000
#define FIN 128
#define HID 16
#define NCLS 40
#define NEDGE 3200000
#define NBUCK 391          // ceil(100000/256): 256 dst-nodes per bucket
#define NCHUNK 782         // ceil(NEDGE/4096)
#define AGG_LD 17          // padded LDS stride (floats) per node row
#define XS_LD 132
#define W_LD 132

// ---------------------------------------------------------------------------
// proj1: xw1h = fp16(x @ W1[1]), xr1 = x @ root1 (fp32). (R5 kernel, measured fine)
// ---------------------------------------------------------------------------
__global__ __launch_bounds__(256) void proj1_kernel(
    const float* __restrict__ x, const float* __restrict__ W1,
    const float* __restrict__ root1,
    __half* __restrict__ xw1h, float* __restrict__ xr1) {
  __shared__ float xs[64 * XS_LD];
  __shared__ float WLt[32 * W_LD];

  int tid = threadIdx.x;
  int node0 = blockIdx.x * 64;

  for (int t = tid; t < 32 * FIN; t += 256) {
    int c = t >> 7, i = t & 127;
    WLt[c * W_LD + i] =
        (c < 16) ? W1[FIN * HID + i * HID + c] : root1[i * HID + (c - 16)];
  }
#pragma unroll
  for (int k = 0; k < 8; ++k) {
    int f = k * 256 + tid;
    int r = f >> 5;
    int cw = f & 31;
    float4 v = make_float4(0.f, 0.f, 0.f, 0.f);
    if (node0 + r < N_NODES)
      v = *(const float4*)(x + (size_t)(node0 + r) * FIN + cw * 4);
    *(float4*)(xs + r * XS_LD + cw * 4) = v;
  }
  __syncthreads();

  int tx = tid & 15;
  int ty = tid >> 4;
  const float* w0 = WLt + (2 * tx) * W_LD;
  const float* w1 = w0 + W_LD;
  const float* xrow = xs + (ty * 4) * XS_LD;

  float acc[4][2] = {{0.f, 0.f}, {0.f, 0.f}, {0.f, 0.f}, {0.f, 0.f}};
#pragma unroll 8
  for (int i = 0; i < FIN; i += 4) {
    float4 b0 = *(const float4*)(w0 + i);
    float4 b1v = *(const float4*)(w1 + i);
#pragma unroll
    for (int k = 0; k < 4; ++k) {
      float4 a = *(const float4*)(xrow + k * XS_LD + i);
      acc[k][0] += a.x * b0.x + a.y * b0.y + a.z * b0.z + a.w * b0.w;
      acc[k][1] += a.x * b1v.x + a.y * b1v.y + a.z * b1v.z + a.w * b1v.w;
    }
  }

  int c0 = 2 * tx;
#pragma unroll
  for (int k = 0; k < 4; ++k) {
    int n = node0 + ty * 4 + k;
    if (n < N_NODES) {
      if (c0 < 16) {
        xw1h[n * HID + c0] = __float2half(acc[k][0]);
        xw1h[n * HID + c0 + 1] = __float2half(acc[k][1]);
      } else {
        xr1[n * HID + (c0 - 16)] = acc[k][0];
        xr1[n * HID + (c0 - 15)] = acc[k][1];
      }
    }
  }
}

// ---------------------------------------------------------------------------
// histB: bucket histogram (391 counters) with LDS pre-aggregation.
// ---------------------------------------------------------------------------
__global__ __launch_bounds__(256) void histB_kernel(
    const int* __restrict__ dst, int* __restrict__ bcnt) {
  __shared__ int hc[NBUCK];
  for (int t = threadIdx.x; t < NBUCK; t += 256) hc[t] = 0;
  __syncthreads();
  int base = blockIdx.x * 4096;
#pragma unroll
  for (int k = 0; k < 16; ++k) {
    int e = base + k * 256 + threadIdx.x;
    if (e < NEDGE) atomicAdd(&hc[dst[e] >> 8], 1);
  }
  __syncthreads();
  for (int t = threadIdx.x; t < NBUCK; t += 256) {
    int v = hc[t];
    if (v) atomicAdd(&bcnt[t], v);
  }
}

// ---------------------------------------------------------------------------
// scan: exclusive scan of 391 counts -> boff[0..391] and gcursor init.
// ---------------------------------------------------------------------------
__global__ __launch_bounds__(512) void scan_kernel(
    const int* __restrict__ bcnt, int* __restrict__ boff,
    int* __restrict__ gcursor) {
  __shared__ int s[512];
  int v = (threadIdx.x < NBUCK) ? bcnt[threadIdx.x] : 0;
  s[threadIdx.x] = v;
  __syncthreads();
  for (int off = 1; off < 512; off <<= 1) {
    int t = (threadIdx.x >= off) ? s[threadIdx.x - off] : 0;
    __syncthreads();
    s[threadIdx.x] += t;
    __syncthreads();
  }
  if (threadIdx.x < NBUCK) {
    int e = s[threadIdx.x] - v;
    boff[threadIdx.x] = e;
    gcursor[threadIdx.x] = e;
  }
  if (threadIdx.x == 0) boff[NBUCK] = NEDGE;
}

// ---------------------------------------------------------------------------
// partA: multi-split partition. Each block = 4096-edge chunk. One global
// cursor atomic per (block,bucket); per-edge rec writes land in a
// block-private contiguous run (L2 write-combines within the XCD).
// rec = src | (dst&255)<<17.
// ---------------------------------------------------------------------------
__global__ __launch_bounds__(256) void partA_kernel(
    const int* __restrict__ src, const int* __restrict__ dst,
    int* __restrict__ gcursor, unsigned* __restrict__ recs) {
  __shared__ int cnt[NBUCK];
  __shared__ int base[NBUCK];
  __shared__ int cur[NBUCK];
  for (int t = threadIdx.x; t < NBUCK; t += 256) {
    cnt[t] = 0;
    cur[t] = 0;
  }
  __syncthreads();

  int ebase = blockIdx.x * 4096;
  unsigned recv[16];
  int bk[16];
#pragma unroll
  for (int k = 0; k < 16; ++k) {
    int e = ebase + k * 256 + threadIdx.x;
    if (e < NEDGE) {
      int d = dst[e];
      int s = src[e];
      bk[k] = d >> 8;
      recv[k] = (unsigned)s | ((unsigned)(d & 255) << 17);
      atomicAdd(&cnt[bk[k]], 1);
    } else {
      bk[k] = -1;
    }
  }
  __syncthreads();
  for (int t = threadIdx.x; t < NBUCK; t += 256) {
    int c = cnt[t];
    base[t] = c ? atomicAdd(&gcursor[t], c) : 0;
  }
  __syncthreads();
#pragma unroll
  for (int k = 0; k < 16; ++k) {
    if (bk[k] >= 0) {
      int off = atomicAdd(&cur[bk[k]], 1);
      recs[base[bk[k]] + off] = recv[k];
    }
  }
}

// ---------------------------------------------------------------------------
// aggL1: one block per bucket (512 thr). LDS fp32 256x16 accumulator (+pad),
// LDS degree. 16 lanes per rec gather fp16 features (L2-resident table).
// Fused mean + xr1 + b1 + ELU epilogue -> hb fp16, degf fp32.
// ---------------------------------------------------------------------------
__global__ __launch_bounds__(512) void aggL1_kernel(
    const int* __restrict__ boff, const unsigned* __restrict__ recs,
    const __half* __restrict__ val, const float* __restrict__ xr1,
    const float* __restrict__ b1, float* __restrict__ degf,
    __half* __restrict__ hb) {
  __shared__ float agg[256 * AGG_LD];
  __shared__ int ldeg[256];
  for (int t = threadIdx.x; t < 256 * AGG_LD; t += 512) agg[t] = 0.f;
  if (threadIdx.x < 256) ldeg[threadIdx.x] = 0;
  __syncthreads();

  int b = blockIdx.x;
  int beg = boff[b], end = boff[b + 1];
  int g = threadIdx.x >> 4;  // 32 rec-groups in flight
  int c = threadIdx.x & 15;
  for (int j = beg + g; j < end; j += 32) {
    unsigned r = recs[j];
    int s = r & 0x1FFFF;
    int dl = r >> 17;
    float v = __half2float(val[s * HID + c]);
    atomicAdd(&agg[dl * AGG_LD + c], v);
    if (c == 0) atomicAdd(&ldeg[dl], 1);
  }
  __syncthreads();

  int n0 = b * 256;
  for (int t = threadIdx.x; t < 256 * HID; t += 512) {
    int nl = t >> 4, cc = t & 15;
    int n = n0 + nl;
    if (n < N_NODES) {
      float d = fmaxf((float)ldeg[nl], 1.0f);
      float a = agg[nl * AGG_LD + cc] / d + xr1[n * HID + cc] + b1[cc];
      a = (a > 0.f) ? a : expm1f(a);
      hb[n * HID + cc] = __float2half(a);
      if (cc == 0) degf[n] = (float)ldeg[nl];
    }
  }
}

// ---------------------------------------------------------------------------
// aggL2: same structure; gathers hb, writes mean-normalized fp32 agg2n.
// ---------------------------------------------------------------------------
__global__ __launch_bounds__(512) void aggL2_kernel(
    const int* __restrict__ boff, const unsigned* __restrict__ recs,
    const __half* __restrict__ val, const float* __restrict__ degf,
    float* __restrict__ agg2n) {
  __shared__ float agg[256 * AGG_LD];
  for (int t = threadIdx.x; t < 256 * AGG_LD; t += 512) agg[t] = 0.f;
  __syncthreads();

  int b = blockIdx.x;
  int beg = boff[b], end = boff[b + 1];
  int g = threadIdx.x >> 4;
  int c = threadIdx.x & 15;
  for (int j = beg + g; j < end; j += 32) {
    unsigned r = recs[j];
    int s = r & 0x1FFFF;
    int dl = r >> 17;
    float v = __half2float(val[s * HID + c]);
    atomicAdd(&agg[dl * AGG_LD + c], v);
  }
  __syncthreads();

  int n0 = b * 256;
  for (int t = threadIdx.x; t < 256 * HID; t += 512) {
    int nl = t >> 4, cc = t & 15;
    int n = n0 + nl;
    if (n < N_NODES)
      agg2n[n * HID + cc] = agg[nl * AGG_LD + cc] / fmaxf(degf[n], 1.0f);
  }
}

// ---------------------------------------------------------------------------
// out: agg2n @ W2[1] + h @ root2 + b2, log_softmax, fp32 store.
// ---------------------------------------------------------------------------
__global__ __launch_bounds__(256) void out_kernel(
    const __half* __restrict__ hb, const float* __restrict__ agg2n,
    const float* __restrict__ W2, const float* __restrict__ root2,
    const float* __restrict__ b2v, float* __restrict__ out) {
  __shared__ float Wl[HID * NCLS];
  __shared__ float Rl[HID * NCLS];
  __shared__ float Bl[NCLS];
  for (int i = threadIdx.x; i < HID * NCLS; i += blockDim.x) {
    Wl[i] = W2[HID * NCLS + i];
    Rl[i] = root2[i];
  }
  if (threadIdx.x < NCLS) Bl[threadIdx.x] = b2v[threadIdx.x];
  __syncthreads();

  int n = blockIdx.x * blockDim.x + threadIdx.x;
  if (n >= N_NODES) return;

  float hv[HID], av[HID];
#pragma unroll
  for (int c = 0; c < HID; ++c) {
    hv[c] = __half2float(hb[n * HID + c]);
    av[c] = agg2n[n * HID + c];
  }
  float logit[NCLS];
#pragma unroll
  for (int j = 0; j < NCLS; ++j) logit[j] = Bl[j];
  for (int c = 0; c < HID; ++c) {
    float hc = hv[c], ac = av[c];
#pragma unroll
    for (int j = 0; j < NCLS; ++j)
      logit[j] += ac * Wl[c * NCLS + j] + hc * Rl[c * NCLS + j];
  }
  float m = -INFINITY;
#pragma unroll
  for (int j = 0; j < NCLS; ++j) m = fmaxf(m, logit[j]);
  float s = 0.f;
#pragma unroll
  for (int j = 0; j < NCLS; ++j) s += expf(logit[j] - m);
  float lse = m + logf(s);
#pragma unroll
  for (int j = 0; j < NCLS; ++j)
    out[(size_t)n * NCLS + j] = logit[j] - lse;
}

extern "C" void kernel_launch(void* const* d_in, const int* in_sizes, int n_in,
                              void* d_out, int out_size, void* d_ws,
                              size_t ws_size, hipStream_t stream) {
  const float* x = (const float*)d_in[0];
  const int* ei = (const int*)d_in[1];  // (2, E): src row then dst row
  const float* W1 = (const float*)d_in[2];
  const float* root1 = (const float*)d_in[3];
  const float* b1 = (const float*)d_in[4];
  const float* W2 = (const float*)d_in[5];
  const float* root2 = (const float*)d_in[6];
  const float* b2v = (const float*)d_in[7];
  float* out = (float*)d_out;

  const int* src = ei;
  const int* dstp = ei + NEDGE;

  // workspace layout (bytes), ~26 MB:
  char* w = (char*)d_ws;
  int* bcnt = (int*)w;         w += 2048;                       // 391 ints
  int* boff = (int*)w;         w += 2048;                       // 392 ints
  int* gcursor = (int*)w;      w += 2048;
  float* degf = (float*)w;     w += (size_t)N_NODES * 4;
  unsigned* recs = (unsigned*)w; w += (size_t)NEDGE * 4;
  __half* xw1h = (__half*)w;   w += (size_t)N_NODES * HID * 2;
  __half* hb = (__half*)w;     w += (size_t)N_NODES * HID * 2;
  float* xr1 = (float*)w;      w += (size_t)N_NODES * HID * 4;
  float* agg2n = (float*)w;    w += (size_t)N_NODES * HID * 4;

  hipMemsetAsync(bcnt, 0, 2048, stream);

  proj1_kernel<<<(N_NODES + 63) / 64, 256, 0, stream>>>(x, W1, root1, xw1h,
                                                        xr1);
  histB_kernel<<<NCHUNK, 256, 0, stream>>>(dstp, bcnt);
  scan_kernel<<<1, 512, 0, stream>>>(bcnt, boff, gcursor);
  partA_kernel<<<NCHUNK, 256, 0, stream>>>(src, dstp, gcursor, recs);
  aggL1_kernel<<<NBUCK, 512, 0, stream>>>(boff, recs, xw1h, xr1, b1, degf, hb);
  aggL2_kernel<<<NBUCK, 512, 0, stream>>>(boff, recs, hb, degf, agg2n);
  out_kernel<<<(N_NODES + 255) / 256, 256, 0, stream>>>(hb, agg2n, W2, root2,
                                                        b2v, out);
}

// Round 8
// 649.511 us; speedup vs baseline: 1.3881x; 1.3881x over previous
//
#include <hip/hip_runtime.h>
#include <hip/hip_bf16.h>

#define N_NODES 100000
#define FIN 128
#define HID 16
#define NCLS 40
#define NEDGE 3200000
#define XS_LD 132   // padded row stride (floats) for x tile
#define W_LD 132    // padded row stride for transposed weight panel

// ---------------------------------------------------------------------------
// proj1: xw1 = x @ W1[1], xr1 = x @ root1 (both fp32).
// Block: 256 threads, 64 nodes. Thread micro-tile: 4 nodes x 2 cols.
// All inner-loop LDS reads are ds_read_b128 (float4).
// ---------------------------------------------------------------------------
__global__ __launch_bounds__(256) void proj1_kernel(
    const float* __restrict__ x, const float* __restrict__ W1,
    const float* __restrict__ root1,
    float* __restrict__ xw1, float* __restrict__ xr1) {
  __shared__ float xs[64 * XS_LD];   // 33 KB
  __shared__ float WLt[32 * W_LD];   // 16.5 KB

  int tid = threadIdx.x;
  int node0 = blockIdx.x * 64;

  for (int t = tid; t < 32 * FIN; t += 256) {
    int c = t >> 7, i = t & 127;
    WLt[c * W_LD + i] =
        (c < 16) ? W1[FIN * HID + i * HID + c] : root1[i * HID + (c - 16)];
  }
#pragma unroll
  for (int k = 0; k < 8; ++k) {
    int f = k * 256 + tid;
    int r = f >> 5;
    int cw = f & 31;
    float4 v = make_float4(0.f, 0.f, 0.f, 0.f);
    if (node0 + r < N_NODES)
      v = *(const float4*)(x + (size_t)(node0 + r) * FIN + cw * 4);
    *(float4*)(xs + r * XS_LD + cw * 4) = v;
  }
  __syncthreads();

  int tx = tid & 15;
  int ty = tid >> 4;
  const float* w0 = WLt + (2 * tx) * W_LD;
  const float* w1 = w0 + W_LD;
  const float* xrow = xs + (ty * 4) * XS_LD;

  float acc[4][2] = {{0.f, 0.f}, {0.f, 0.f}, {0.f, 0.f}, {0.f, 0.f}};
#pragma unroll 8
  for (int i = 0; i < FIN; i += 4) {
    float4 b0 = *(const float4*)(w0 + i);
    float4 b1v = *(const float4*)(w1 + i);
#pragma unroll
    for (int k = 0; k < 4; ++k) {
      float4 a = *(const float4*)(xrow + k * XS_LD + i);
      acc[k][0] += a.x * b0.x + a.y * b0.y + a.z * b0.z + a.w * b0.w;
      acc[k][1] += a.x * b1v.x + a.y * b1v.y + a.z * b1v.z + a.w * b1v.w;
    }
  }

  int c0 = 2 * tx;
#pragma unroll
  for (int k = 0; k < 4; ++k) {
    int n = node0 + ty * 4 + k;
    if (n < N_NODES) {
      float* dstp = (c0 < 16) ? (xw1 + n * HID + c0) : (xr1 + n * HID + c0 - 16);
      dstp[0] = acc[k][0];
      dstp[1] = acc[k][1];
    }
  }
}

// ---------------------------------------------------------------------------
// scatter: per-edge fp32 scatter-add of 16 channels; thread t -> edge t/16,
// channel t%16. Measured at the fabric atomic roofline (~308 G ops/s, R2).
// DO_DEG: channel-0 lane also counts degree.
// ---------------------------------------------------------------------------
template <bool DO_DEG>
__global__ __launch_bounds__(256) void scatter_kernel(
    const int* __restrict__ src, const int* __restrict__ dst,
    const float* __restrict__ val, float* __restrict__ agg,
    float* __restrict__ deg) {
  int t = blockIdx.x * 256 + threadIdx.x;   // grid sized exactly NEDGE*16
  int e = t >> 4;
  int c = t & 15;
  int s = src[e];
  int d = dst[e];
  atomicAdd(&agg[d * HID + c], val[s * HID + c]);
  if (DO_DEG && c == 0) atomicAdd(&deg[d], 1.0f);
}

// ---------------------------------------------------------------------------
// hidden: h = elu(agg1/deg + xr1 + b1), float4-vectorized (4 ch/thread).
// grid is CEIL(N*4/256) -> guard needed (R7 bug: truncated grid skipped 32 nodes).
// ---------------------------------------------------------------------------
__global__ __launch_bounds__(256) void hidden_kernel(
    const float4* __restrict__ agg1, const float4* __restrict__ xr1,
    const float* __restrict__ b1, const float* __restrict__ deg,
    float4* __restrict__ h) {
  int t = blockIdx.x * 256 + threadIdx.x;
  if (t >= N_NODES * 4) return;
  int n = t >> 2;
  int q = t & 3;
  float inv = 1.0f / fmaxf(deg[n], 1.0f);
  float4 a = agg1[t];
  float4 r = xr1[t];
  const float4 bb = *(const float4*)(b1 + q * 4);
  float4 o;
  o.x = a.x * inv + r.x + bb.x;
  o.y = a.y * inv + r.y + bb.y;
  o.z = a.z * inv + r.z + bb.z;
  o.w = a.w * inv + r.w + bb.w;
  o.x = (o.x > 0.f) ? o.x : expm1f(o.x);
  o.y = (o.y > 0.f) ? o.y : expm1f(o.y);
  o.z = (o.z > 0.f) ? o.z : expm1f(o.z);
  o.w = (o.w > 0.f) ? o.w : expm1f(o.w);
  h[t] = o;
}

// ---------------------------------------------------------------------------
// out: (agg2/deg) @ W2[1] + h @ root2 + b2, log_softmax, fp32 store.
// ---------------------------------------------------------------------------
__global__ __launch_bounds__(256) void out_kernel(
    const float* __restrict__ h, const float* __restrict__ agg2,
    const float* __restrict__ deg, const float* __restrict__ W2,
    const float* __restrict__ root2, const float* __restrict__ b2v,
    float* __restrict__ out) {
  __shared__ float Wl[HID * NCLS];
  __shared__ float Rl[HID * NCLS];
  __shared__ float Bl[NCLS];
  for (int i = threadIdx.x; i < HID * NCLS; i += blockDim.x) {
    Wl[i] = W2[HID * NCLS + i];
    Rl[i] = root2[i];
  }
  if (threadIdx.x < NCLS) Bl[threadIdx.x] = b2v[threadIdx.x];
  __syncthreads();

  int n = blockIdx.x * blockDim.x + threadIdx.x;
  if (n >= N_NODES) return;

  float inv = 1.0f / fmaxf(deg[n], 1.0f);
  float hv[HID], av[HID];
#pragma unroll
  for (int c = 0; c < HID; ++c) {
    hv[c] = h[n * HID + c];
    av[c] = agg2[n * HID + c] * inv;
  }
  float logit[NCLS];
#pragma unroll
  for (int j = 0; j < NCLS; ++j) logit[j] = Bl[j];
  for (int c = 0; c < HID; ++c) {
    float hc = hv[c], ac = av[c];
#pragma unroll
    for (int j = 0; j < NCLS; ++j)
      logit[j] += ac * Wl[c * NCLS + j] + hc * Rl[c * NCLS + j];
  }
  float m = -INFINITY;
#pragma unroll
  for (int j = 0; j < NCLS; ++j) m = fmaxf(m, logit[j]);
  float s = 0.f;
#pragma unroll
  for (int j = 0; j < NCLS; ++j) s += expf(logit[j] - m);
  float lse = m + logf(s);
#pragma unroll
  for (int j = 0; j < NCLS; ++j)
    out[(size_t)n * NCLS + j] = logit[j] - lse;
}

extern "C" void kernel_launch(void* const* d_in, const int* in_sizes, int n_in,
                              void* d_out, int out_size, void* d_ws,
                              size_t ws_size, hipStream_t stream) {
  const float* x = (const float*)d_in[0];
  const int* ei = (const int*)d_in[1];  // (2, E): src row then dst row
  const float* W1 = (const float*)d_in[2];
  const float* root1 = (const float*)d_in[3];
  const float* b1 = (const float*)d_in[4];
  const float* W2 = (const float*)d_in[5];
  const float* root2 = (const float*)d_in[6];
  const float* b2v = (const float*)d_in[7];
  float* out = (float*)d_out;

  const int* src = ei;
  const int* dstp = ei + NEDGE;

  // workspace (floats): [deg N][agg1 16N][agg2 16N][xw1 16N][xr1 16N][h 16N]
  // = 81N floats = 32.4 MB
  float* ws = (float*)d_ws;
  float* deg = ws;                  // N
  float* agg1 = ws + N_NODES;       // 16N
  float* agg2 = ws + 17 * N_NODES;  // 16N
  float* xw1 = ws + 33 * N_NODES;   // 16N
  float* xr1 = ws + 49 * N_NODES;   // 16N
  float* h = ws + 65 * N_NODES;     // 16N

  // zero deg + agg1 + agg2 in one shot (13.2 MB)
  hipMemsetAsync(deg, 0, (size_t)33 * N_NODES * sizeof(float), stream);

  proj1_kernel<<<(N_NODES + 63) / 64, 256, 0, stream>>>(x, W1, root1, xw1,
                                                        xr1);
  scatter_kernel<true><<<NEDGE * 16 / 256, 256, 0, stream>>>(src, dstp, xw1,
                                                             agg1, deg);
  hidden_kernel<<<(N_NODES * 4 + 255) / 256, 256, 0, stream>>>(
      (const float4*)agg1, (const float4*)xr1, b1, deg, (float4*)h);
  scatter_kernel<false><<<NEDGE * 16 / 256, 256, 0, stream>>>(src, dstp, h,
                                                              agg2, nullptr);
  out_kernel<<<(N_NODES + 255) / 256, 256, 0, stream>>>(h, agg2, deg, W2,
                                                        root2, b2v, out);
}